// Round 3
// baseline (326.659 us; speedup 1.0000x reference)
//
#include <hip/hip_runtime.h>

#define N_NODES   10000
#define IN_DIM    512
#define HID_DIM   512
#define OUT_DIM   256
#define N_CLASSES 8
#define N_GRAPHS  64

typedef __attribute__((ext_vector_type(8))) __bf16 bf16x8;
typedef __attribute__((ext_vector_type(4))) float f32x4;
typedef __attribute__((ext_vector_type(8))) unsigned short ushort8;

__device__ __forceinline__ unsigned short f2bf(float f) {
    union { float f; unsigned int u; } v; v.f = f;
    unsigned int r = v.u + 0x7FFFu + ((v.u >> 16) & 1u);   // RTNE
    return (unsigned short)(r >> 16);
}
__device__ __forceinline__ float bf2f(unsigned short u) {
    union { unsigned int u; float f; } v; v.u = ((unsigned int)u) << 16;
    return v.f;
}

// ---------------- degree count ----------------
__global__ void count_deg_kernel(const int* __restrict__ dst, int* __restrict__ cnt, int E) {
    int e = blockIdx.x * blockDim.x + threadIdx.x;
    if (e < E) atomicAdd(&cnt[dst[e]], 1);
}

// ---------------- dinv + per-graph node counts ----------------
__global__ void node_prep_kernel(const int* __restrict__ cnt, float* __restrict__ dinv,
                                 const int* __restrict__ batch, float* __restrict__ gcnt, int n) {
    int i = blockIdx.x * blockDim.x + threadIdx.x;
    if (i < n) {
        dinv[i] = rsqrtf((float)(cnt[i] + 1));   // self-loop => deg >= 1
        atomicAdd(&gcnt[batch[i]], 1.0f);
    }
}

// ---------------- exclusive scan (one block) ----------------
__global__ __launch_bounds__(1024) void scan_kernel(const int* __restrict__ cnt,
                                                    int* __restrict__ offs,
                                                    int* __restrict__ pos, int n) {
    __shared__ int partial[1024];
    int tid = threadIdx.x;
    const int CH = (n + 1023) >> 10;
    int base = tid * CH;
    int s = 0;
    for (int i = 0; i < CH; i++) { int idx = base + i; if (idx < n) s += cnt[idx]; }
    partial[tid] = s;
    __syncthreads();
    for (int off = 1; off < 1024; off <<= 1) {
        int v = (tid >= off) ? partial[tid - off] : 0;
        __syncthreads();
        partial[tid] += v;
        __syncthreads();
    }
    int run = (tid > 0) ? partial[tid - 1] : 0;
    for (int i = 0; i < CH; i++) {
        int idx = base + i;
        if (idx < n) { offs[idx] = run; pos[idx] = run; run += cnt[idx]; }
    }
    if (tid == 0) offs[n] = partial[1023];
}

// ---------------- bucket edges into CSR (by dst) ----------------
__global__ void fill_csr_kernel(const int* __restrict__ src, const int* __restrict__ dst,
                                const float* __restrict__ dinv, int* __restrict__ pos,
                                int* __restrict__ csrs, float* __restrict__ csrn, int E) {
    int e = blockIdx.x * blockDim.x + threadIdx.x;
    if (e < E) {
        int s = src[e], d = dst[e];
        int p = atomicAdd(&pos[d], 1);
        csrs[p] = s;
        csrn[p] = dinv[s] * dinv[d];
    }
}

// ---------------- W[K][N] fp32 -> Wt[N][K] bf16 (tiled transpose) ----------------
__global__ __launch_bounds__(256) void transposeW_kernel(const float* __restrict__ W,
                                                         unsigned short* __restrict__ Wt,
                                                         int K, int N) {
    __shared__ float t[32][33];
    int bn = blockIdx.x * 32;   // n base
    int bk = blockIdx.y * 32;   // k base
    int tx = threadIdx.x, ty = threadIdx.y;   // 32 x 8
    #pragma unroll
    for (int j = 0; j < 32; j += 8)
        t[ty + j][tx] = W[(size_t)(bk + ty + j) * N + bn + tx];
    __syncthreads();
    #pragma unroll
    for (int j = 0; j < 32; j += 8)
        Wt[(size_t)(bn + ty + j) * K + bk + tx] = f2bf(t[tx][ty + j]);
}

// ---------------- bf16 MFMA GEMM: C[M,N] = A[M,K] @ Bt[N,K]^T ----------------
// 128x128 tile, BK=32, 4 waves (2x2), 4x4 fragments of 16x16x32 per wave.
// LDS k-stride padded to 40 elems: bank = (20*row + 4*g) % 32 -> 2 lanes/bank (free).
template<bool A_F32, bool OUT_BF16>
__global__ __launch_bounds__(256) void mfma_gemm_kernel(const void* __restrict__ Ap,
                                                        const unsigned short* __restrict__ Bt,
                                                        void* __restrict__ Cp,
                                                        int M, int N, int K) {
    constexpr int BM = 128, BN = 128, BK = 32, PK = 40;
    __shared__ unsigned short As[BM * PK];
    __shared__ unsigned short Bs[BN * PK];
    int tid  = threadIdx.x;
    int lane = tid & 63;
    int wid  = tid >> 6;
    int wm = wid >> 1, wn = wid & 1;
    int row0 = blockIdx.x * BM, col0 = blockIdx.y * BN;

    f32x4 acc[4][4] = {};

    for (int k0 = 0; k0 < K; k0 += BK) {
        #pragma unroll
        for (int i = 0; i < 2; i++) {
            int l  = tid + i * 256;          // 512 slots of 8 bf16
            int r  = l >> 2;                 // 0..127
            int cg = (l & 3) << 3;           // 0,8,16,24
            int gr = row0 + r;
            ushort8 av = {0, 0, 0, 0, 0, 0, 0, 0};
            if (A_F32) {
                const float* A = (const float*)Ap;
                if (gr < M) {
                    float4 f0 = *reinterpret_cast<const float4*>(&A[(size_t)gr * K + k0 + cg]);
                    float4 f1 = *reinterpret_cast<const float4*>(&A[(size_t)gr * K + k0 + cg + 4]);
                    av[0] = f2bf(f0.x); av[1] = f2bf(f0.y); av[2] = f2bf(f0.z); av[3] = f2bf(f0.w);
                    av[4] = f2bf(f1.x); av[5] = f2bf(f1.y); av[6] = f2bf(f1.z); av[7] = f2bf(f1.w);
                }
            } else {
                const unsigned short* A = (const unsigned short*)Ap;
                if (gr < M) av = *reinterpret_cast<const ushort8*>(&A[(size_t)gr * K + k0 + cg]);
            }
            *reinterpret_cast<ushort8*>(&As[r * PK + cg]) = av;
            // B tile: Bt is [N][K] bf16; N,K are exact multiples — no guard
            *reinterpret_cast<ushort8*>(&Bs[r * PK + cg]) =
                *reinterpret_cast<const ushort8*>(&Bt[(size_t)(col0 + r) * K + k0 + cg]);
        }
        __syncthreads();
        int kk = (lane >> 4) << 3;                       // 0,8,16,24
        int ra = (wm * 64 + (lane & 15)) * PK + kk;
        int rb = (wn * 64 + (lane & 15)) * PK + kk;
        bf16x8 a[4], b[4];
        #pragma unroll
        for (int m = 0; m < 4; m++)
            a[m] = *reinterpret_cast<const bf16x8*>(&As[ra + m * 16 * PK]);
        #pragma unroll
        for (int nn = 0; nn < 4; nn++)
            b[nn] = *reinterpret_cast<const bf16x8*>(&Bs[rb + nn * 16 * PK]);
        #pragma unroll
        for (int m = 0; m < 4; m++)
            #pragma unroll
            for (int nn = 0; nn < 4; nn++)
                acc[m][nn] = __builtin_amdgcn_mfma_f32_16x16x32_bf16(a[m], b[nn], acc[m][nn], 0, 0, 0);
        __syncthreads();
    }

    // C/D layout (HW-verified): col = lane&15, row = (lane>>4)*4 + reg
    int rbase = row0 + wm * 64 + ((lane >> 4) << 2);
    int cbase = col0 + wn * 64 + (lane & 15);
    #pragma unroll
    for (int m = 0; m < 4; m++) {
        #pragma unroll
        for (int nn = 0; nn < 4; nn++) {
            #pragma unroll
            for (int j = 0; j < 4; j++) {
                int row = rbase + m * 16 + j;
                if (row < M) {
                    int col = cbase + nn * 16;
                    if (OUT_BF16) ((unsigned short*)Cp)[(size_t)row * N + col] = f2bf(acc[m][nn][j]);
                    else          ((float*)Cp)[(size_t)row * N + col] = acc[m][nn][j];
                }
            }
        }
    }
}

// ---------------- aggregation over bf16 h, fp32 accumulate, bf16 out (+bias+relu) ----------------
template<int F>
__global__ void aggregate_bf16_kernel(const unsigned short* __restrict__ h,
                                      const int* __restrict__ offs, const int* __restrict__ csrs,
                                      const float* __restrict__ csrn, const float* __restrict__ dinv,
                                      const float* __restrict__ bias,
                                      unsigned short* __restrict__ outp, int n) {
    int i = blockIdx.x;
    int f = threadIdx.x * 4;   // blockDim = F/4
    float di = dinv[i], w0 = di * di;
    ushort4 hv = *reinterpret_cast<const ushort4*>(&h[(size_t)i * F + f]);
    float ax = bf2f(hv.x) * w0, ay = bf2f(hv.y) * w0;
    float az = bf2f(hv.z) * w0, aw = bf2f(hv.w) * w0;
    int p1 = offs[i + 1];
    for (int p = offs[i]; p < p1; p++) {
        int s = csrs[p];
        float w = csrn[p];
        ushort4 v = *reinterpret_cast<const ushort4*>(&h[(size_t)s * F + f]);
        ax = fmaf(w, bf2f(v.x), ax); ay = fmaf(w, bf2f(v.y), ay);
        az = fmaf(w, bf2f(v.z), az); aw = fmaf(w, bf2f(v.w), aw);
    }
    float4 bv = *reinterpret_cast<const float4*>(&bias[f]);
    ushort4 r;
    r.x = f2bf(fmaxf(ax + bv.x, 0.f)); r.y = f2bf(fmaxf(ay + bv.y, 0.f));
    r.z = f2bf(fmaxf(az + bv.z, 0.f)); r.w = f2bf(fmaxf(aw + bv.w, 0.f));
    *reinterpret_cast<ushort4*>(&outp[(size_t)i * F + f]) = r;
}

// ---------------- layer-2 aggregation fused with mean-pool accumulation (fp32 h2) ----------------
__global__ void agg_pool_kernel(const float* __restrict__ h, const int* __restrict__ offs,
                                const int* __restrict__ csrs, const float* __restrict__ csrn,
                                const float* __restrict__ dinv, const float* __restrict__ bias,
                                const int* __restrict__ batch, float* __restrict__ pooled, int n) {
    constexpr int F = OUT_DIM;
    int i = blockIdx.x;
    int f = threadIdx.x * 4;   // 64 threads * 4 = 256
    float di = dinv[i], w0 = di * di;
    float4 hv = *reinterpret_cast<const float4*>(&h[(size_t)i * F + f]);
    float ax = hv.x * w0, ay = hv.y * w0, az = hv.z * w0, aw = hv.w * w0;
    int p1 = offs[i + 1];
    for (int p = offs[i]; p < p1; p++) {
        int s = csrs[p];
        float w = csrn[p];
        float4 v = *reinterpret_cast<const float4*>(&h[(size_t)s * F + f]);
        ax = fmaf(w, v.x, ax); ay = fmaf(w, v.y, ay);
        az = fmaf(w, v.z, az); aw = fmaf(w, v.w, aw);
    }
    float4 bv = *reinterpret_cast<const float4*>(&bias[f]);
    float rx = fmaxf(ax + bv.x, 0.f), ry = fmaxf(ay + bv.y, 0.f);
    float rz = fmaxf(az + bv.z, 0.f), rw = fmaxf(aw + bv.w, 0.f);
    int g = batch[i];
    atomicAdd(&pooled[(size_t)g * F + f + 0], rx);
    atomicAdd(&pooled[(size_t)g * F + f + 1], ry);
    atomicAdd(&pooled[(size_t)g * F + f + 2], rz);
    atomicAdd(&pooled[(size_t)g * F + f + 3], rw);
}

// ---------------- mean + classifier head ----------------
__global__ void final_kernel(const float* __restrict__ pooled, const float* __restrict__ gcnt,
                             const float* __restrict__ Wl, const float* __restrict__ bl,
                             float* __restrict__ out) {
    int t = threadIdx.x;           // 512 threads
    int g = t >> 3, c = t & 7;
    const float* pr = &pooled[(size_t)g * OUT_DIM];
    float s = 0.f;
    for (int k = 0; k < OUT_DIM; k++) s = fmaf(pr[k], Wl[k * N_CLASSES + c], s);
    float inv = 1.0f / fmaxf(gcnt[g], 1.0f);
    out[g * N_CLASSES + c] = s * inv + bl[c];
}

extern "C" void kernel_launch(void* const* d_in, const int* in_sizes, int n_in,
                              void* d_out, int out_size, void* d_ws, size_t ws_size,
                              hipStream_t stream) {
    const float* x   = (const float*)d_in[0];
    const float* W1  = (const float*)d_in[1];
    const float* b1  = (const float*)d_in[2];
    const float* W2  = (const float*)d_in[3];
    const float* b2  = (const float*)d_in[4];
    const float* Wl  = (const float*)d_in[5];
    const float* bl  = (const float*)d_in[6];
    const int*   ei  = (const int*)d_in[7];
    const int*   bat = (const int*)d_in[8];
    float* out = (float*)d_out;

    const int n = N_NODES;
    const int E = in_sizes[7] / 2;
    const int* src = ei;
    const int* dst = ei + E;

    // workspace layout (~33 MB)
    float*          h2    = (float*)d_ws;                              // n*256 fp32
    unsigned short* h1b   = (unsigned short*)(h2 + (size_t)n * OUT_DIM);  // n*512 bf16
    unsigned short* agg1b = h1b + (size_t)n * HID_DIM;                 // n*512 bf16
    unsigned short* W1t   = agg1b + (size_t)n * HID_DIM;               // 512*512 bf16
    unsigned short* W2t   = W1t + IN_DIM * HID_DIM;                    // 256*512 bf16
    int*   cnt  = (int*)(W2t + HID_DIM * OUT_DIM);
    int*   offs = cnt + n;                                             // n+1
    int*   pos  = offs + n + 1;                                        // n
    int*   csrs = pos + n;                                             // E
    float* csrn = (float*)(csrs + E);                                  // E
    float* dinv = csrn + E;                                            // n
    float* gcnt = dinv + n;                                            // 64
    float* pooled = gcnt + N_GRAPHS;                                   // 64*256

    hipMemsetAsync(cnt, 0, n * sizeof(int), stream);
    hipMemsetAsync(gcnt, 0, (N_GRAPHS + N_GRAPHS * OUT_DIM) * sizeof(float), stream);

    count_deg_kernel<<<(E + 255) / 256, 256, 0, stream>>>(dst, cnt, E);
    node_prep_kernel<<<(n + 255) / 256, 256, 0, stream>>>(cnt, dinv, bat, gcnt, n);
    scan_kernel<<<1, 1024, 0, stream>>>(cnt, offs, pos, n);
    fill_csr_kernel<<<(E + 255) / 256, 256, 0, stream>>>(src, dst, dinv, pos, csrs, csrn, E);

    // weight transposes (fp32 -> bf16 [N][K])
    transposeW_kernel<<<dim3(HID_DIM / 32, IN_DIM / 32), dim3(32, 8), 0, stream>>>(W1, W1t, IN_DIM, HID_DIM);
    transposeW_kernel<<<dim3(OUT_DIM / 32, HID_DIM / 32), dim3(32, 8), 0, stream>>>(W2, W2t, HID_DIM, OUT_DIM);

    // layer 1: h1b = bf16(x @ W1) ; agg1b = bf16(relu(A_norm @ h1 + b1))
    dim3 g1((n + 127) / 128, HID_DIM / 128);
    mfma_gemm_kernel<true, true><<<g1, 256, 0, stream>>>(x, W1t, h1b, n, HID_DIM, IN_DIM);
    aggregate_bf16_kernel<HID_DIM><<<n, HID_DIM / 4, 0, stream>>>(h1b, offs, csrs, csrn, dinv, b1, agg1b, n);

    // layer 2: h2 = agg1b @ W2 (fp32 out) ; fused agg+pool
    dim3 g2((n + 127) / 128, OUT_DIM / 128);
    mfma_gemm_kernel<false, false><<<g2, 256, 0, stream>>>(agg1b, W2t, h2, n, OUT_DIM, HID_DIM);
    agg_pool_kernel<<<n, OUT_DIM / 4, 0, stream>>>(h2, offs, csrs, csrn, dinv, b2, bat, pooled, n);

    final_kernel<<<1, N_GRAPHS * N_CLASSES, 0, stream>>>(pooled, gcnt, Wl, bl, out);
}

// Round 4
// 254.927 us; speedup vs baseline: 1.2814x; 1.2814x over previous
//
#include <hip/hip_runtime.h>

#define N_NODES   10000
#define IN_DIM    512
#define HID_DIM   512
#define OUT_DIM   256
#define N_CLASSES 8
#define N_GRAPHS  64

typedef __attribute__((ext_vector_type(8))) __bf16 bf16x8;
typedef __attribute__((ext_vector_type(4))) float f32x4;
typedef __attribute__((ext_vector_type(8))) unsigned short ushort8;
typedef __attribute__((ext_vector_type(4))) unsigned short ushort4v;

__device__ __forceinline__ unsigned short f2bf(float f) {
    union { float f; unsigned int u; } v; v.f = f;
    unsigned int r = v.u + 0x7FFFu + ((v.u >> 16) & 1u);   // RTNE
    return (unsigned short)(r >> 16);
}
__device__ __forceinline__ float bf2f(unsigned short u) {
    union { unsigned int u; float f; } v; v.u = ((unsigned int)u) << 16;
    return v.f;
}

// ---------------- degree count ----------------
__global__ void count_deg_kernel(const int* __restrict__ dst, int* __restrict__ cnt, int E) {
    int e = blockIdx.x * blockDim.x + threadIdx.x;
    if (e < E) atomicAdd(&cnt[dst[e]], 1);
}

// ---------------- dinv ----------------
__global__ void node_prep_kernel(const int* __restrict__ cnt, float* __restrict__ dinv, int n) {
    int i = blockIdx.x * blockDim.x + threadIdx.x;
    if (i < n) dinv[i] = rsqrtf((float)(cnt[i] + 1));   // self-loop => deg >= 1
}

// ---------------- graph boundaries from sorted batch ----------------
// start[g] = first node index with batch >= g ; start[N_GRAPHS] = n
__global__ void bounds_kernel(const int* __restrict__ batch, int* __restrict__ start, int n) {
    int i = blockIdx.x * blockDim.x + threadIdx.x;
    if (i < n) {
        int b = batch[i];
        int bn = (i + 1 < n) ? batch[i + 1] : N_GRAPHS;
        for (int g = b + 1; g <= bn; g++) start[g] = i + 1;
        if (i == 0) for (int g = 0; g <= b; g++) start[g] = 0;
    }
}

// ---------------- exclusive scan (one block) ----------------
__global__ __launch_bounds__(1024) void scan_kernel(const int* __restrict__ cnt,
                                                    int* __restrict__ offs,
                                                    int* __restrict__ pos, int n) {
    __shared__ int partial[1024];
    int tid = threadIdx.x;
    const int CH = (n + 1023) >> 10;
    int base = tid * CH;
    int s = 0;
    for (int i = 0; i < CH; i++) { int idx = base + i; if (idx < n) s += cnt[idx]; }
    partial[tid] = s;
    __syncthreads();
    for (int off = 1; off < 1024; off <<= 1) {
        int v = (tid >= off) ? partial[tid - off] : 0;
        __syncthreads();
        partial[tid] += v;
        __syncthreads();
    }
    int run = (tid > 0) ? partial[tid - 1] : 0;
    for (int i = 0; i < CH; i++) {
        int idx = base + i;
        if (idx < n) { offs[idx] = run; pos[idx] = run; run += cnt[idx]; }
    }
    if (tid == 0) offs[n] = partial[1023];
}

// ---------------- bucket edges into CSR (by dst) ----------------
__global__ void fill_csr_kernel(const int* __restrict__ src, const int* __restrict__ dst,
                                const float* __restrict__ dinv, int* __restrict__ pos,
                                int* __restrict__ csrs, float* __restrict__ csrn, int E) {
    int e = blockIdx.x * blockDim.x + threadIdx.x;
    if (e < E) {
        int s = src[e], d = dst[e];
        int p = atomicAdd(&pos[d], 1);
        csrs[p] = s;
        csrn[p] = dinv[s] * dinv[d];
    }
}

// ---------------- W[K][N] fp32 -> Wt[N][K] bf16 (tiled transpose) ----------------
__global__ __launch_bounds__(256) void transposeW_kernel(const float* __restrict__ W,
                                                         unsigned short* __restrict__ Wt,
                                                         int K, int N) {
    __shared__ float t[32][33];
    int bn = blockIdx.x * 32;
    int bk = blockIdx.y * 32;
    int tx = threadIdx.x, ty = threadIdx.y;   // 32 x 8
    #pragma unroll
    for (int j = 0; j < 32; j += 8)
        t[ty + j][tx] = W[(size_t)(bk + ty + j) * N + bn + tx];
    __syncthreads();
    #pragma unroll
    for (int j = 0; j < 32; j += 8)
        Wt[(size_t)(bn + ty + j) * K + bk + tx] = f2bf(t[tx][ty + j]);
}

// ---------------- bf16 MFMA GEMM: C[M,N] = A[M,K] @ Bt[N,K]^T ----------------
// BMxBN tile, BK=32, 4 waves (2x2), (BM/32)x(BN/32) fragments of 16x16x32 per wave.
template<int BM, int BN, bool A_F32, bool OUT_BF16>
__global__ __launch_bounds__(256) void mfma_gemm_kernel(const void* __restrict__ Ap,
                                                        const unsigned short* __restrict__ Bt,
                                                        void* __restrict__ Cp,
                                                        int M, int N, int K) {
    constexpr int BK = 32, PK = 40;
    constexpr int FM = BM / 32, FN = BN / 32;
    __shared__ unsigned short As[BM * PK];
    __shared__ unsigned short Bs[BN * PK];
    int tid  = threadIdx.x;
    int lane = tid & 63;
    int wid  = tid >> 6;
    int wm = wid >> 1, wn = wid & 1;
    int row0 = blockIdx.x * BM, col0 = blockIdx.y * BN;

    f32x4 acc[FM][FN] = {};

    for (int k0 = 0; k0 < K; k0 += BK) {
        #pragma unroll
        for (int i = 0; i < BM * 4 / 256; i++) {   // A: BM rows x 4 ushort8-slots
            int l  = tid + i * 256;
            int r  = l >> 2;
            int cg = (l & 3) << 3;
            int gr = row0 + r;
            ushort8 av = {0, 0, 0, 0, 0, 0, 0, 0};
            if (A_F32) {
                const float* A = (const float*)Ap;
                if (gr < M) {
                    float4 f0 = *reinterpret_cast<const float4*>(&A[(size_t)gr * K + k0 + cg]);
                    float4 f1 = *reinterpret_cast<const float4*>(&A[(size_t)gr * K + k0 + cg + 4]);
                    av[0] = f2bf(f0.x); av[1] = f2bf(f0.y); av[2] = f2bf(f0.z); av[3] = f2bf(f0.w);
                    av[4] = f2bf(f1.x); av[5] = f2bf(f1.y); av[6] = f2bf(f1.z); av[7] = f2bf(f1.w);
                }
            } else {
                const unsigned short* A = (const unsigned short*)Ap;
                if (gr < M) av = *reinterpret_cast<const ushort8*>(&A[(size_t)gr * K + k0 + cg]);
            }
            *reinterpret_cast<ushort8*>(&As[r * PK + cg]) = av;
        }
        #pragma unroll
        for (int i = 0; i < BN * 4 / 256; i++) {   // B: BN rows x 4 slots (N,K exact)
            int l  = tid + i * 256;
            int r  = l >> 2;
            int cg = (l & 3) << 3;
            *reinterpret_cast<ushort8*>(&Bs[r * PK + cg]) =
                *reinterpret_cast<const ushort8*>(&Bt[(size_t)(col0 + r) * K + k0 + cg]);
        }
        __syncthreads();
        int kk = (lane >> 4) << 3;
        int ra = (wm * (BM / 2) + (lane & 15)) * PK + kk;
        int rb = (wn * (BN / 2) + (lane & 15)) * PK + kk;
        bf16x8 a[FM], b[FN];
        #pragma unroll
        for (int m = 0; m < FM; m++)
            a[m] = *reinterpret_cast<const bf16x8*>(&As[ra + m * 16 * PK]);
        #pragma unroll
        for (int nn = 0; nn < FN; nn++)
            b[nn] = *reinterpret_cast<const bf16x8*>(&Bs[rb + nn * 16 * PK]);
        #pragma unroll
        for (int m = 0; m < FM; m++)
            #pragma unroll
            for (int nn = 0; nn < FN; nn++)
                acc[m][nn] = __builtin_amdgcn_mfma_f32_16x16x32_bf16(a[m], b[nn], acc[m][nn], 0, 0, 0);
        __syncthreads();
    }

    // C/D layout (HW-verified): col = lane&15, row = (lane>>4)*4 + reg
    int rbase = row0 + wm * (BM / 2) + ((lane >> 4) << 2);
    int cbase = col0 + wn * (BN / 2) + (lane & 15);
    #pragma unroll
    for (int m = 0; m < FM; m++) {
        #pragma unroll
        for (int nn = 0; nn < FN; nn++) {
            #pragma unroll
            for (int j = 0; j < 4; j++) {
                int row = rbase + m * 16 + j;
                if (row < M) {
                    int col = cbase + nn * 16;
                    if (OUT_BF16) ((unsigned short*)Cp)[(size_t)row * N + col] = f2bf(acc[m][nn][j]);
                    else          ((float*)Cp)[(size_t)row * N + col] = acc[m][nn][j];
                }
            }
        }
    }
}

// ---------------- layer-1 aggregation: wave per node, F=512, bf16 in/out ----------------
__global__ __launch_bounds__(256) void agg512_kernel(const unsigned short* __restrict__ h,
                                                     const int* __restrict__ offs,
                                                     const int* __restrict__ csrs,
                                                     const float* __restrict__ csrn,
                                                     const float* __restrict__ dinv,
                                                     const float* __restrict__ bias,
                                                     unsigned short* __restrict__ outp, int n) {
    int wid = threadIdx.x >> 6, lane = threadIdx.x & 63;
    int i = blockIdx.x * 4 + wid;
    if (i >= n) return;
    int f = lane * 8;
    float di = dinv[i], w0 = di * di;
    ushort8 hv = *reinterpret_cast<const ushort8*>(&h[(size_t)i * 512 + f]);
    float acc[8];
    #pragma unroll
    for (int j = 0; j < 8; j++) acc[j] = bf2f(hv[j]) * w0;
    int p0 = offs[i], p1 = offs[i + 1];
    if (p0 < p1) {
        int s = csrs[p0]; float w = csrn[p0];
        ushort8 v = *reinterpret_cast<const ushort8*>(&h[(size_t)s * 512 + f]);
        for (int p = p0 + 1; p < p1; p++) {
            int s2 = csrs[p]; float w2 = csrn[p];
            ushort8 v2 = *reinterpret_cast<const ushort8*>(&h[(size_t)s2 * 512 + f]);
            #pragma unroll
            for (int j = 0; j < 8; j++) acc[j] = fmaf(w, bf2f(v[j]), acc[j]);
            w = w2; v = v2;
        }
        #pragma unroll
        for (int j = 0; j < 8; j++) acc[j] = fmaf(w, bf2f(v[j]), acc[j]);
    }
    float4 b0 = *reinterpret_cast<const float4*>(&bias[f]);
    float4 b1 = *reinterpret_cast<const float4*>(&bias[f + 4]);
    ushort8 r;
    r[0] = f2bf(fmaxf(acc[0] + b0.x, 0.f)); r[1] = f2bf(fmaxf(acc[1] + b0.y, 0.f));
    r[2] = f2bf(fmaxf(acc[2] + b0.z, 0.f)); r[3] = f2bf(fmaxf(acc[3] + b0.w, 0.f));
    r[4] = f2bf(fmaxf(acc[4] + b1.x, 0.f)); r[5] = f2bf(fmaxf(acc[5] + b1.y, 0.f));
    r[6] = f2bf(fmaxf(acc[6] + b1.z, 0.f)); r[7] = f2bf(fmaxf(acc[7] + b1.w, 0.f));
    *reinterpret_cast<ushort8*>(&outp[(size_t)i * 512 + f]) = r;
}

// ---------------- layer-2 aggregation: wave per node, F=256, bf16 in/out ----------------
__global__ __launch_bounds__(256) void agg256_kernel(const unsigned short* __restrict__ h,
                                                     const int* __restrict__ offs,
                                                     const int* __restrict__ csrs,
                                                     const float* __restrict__ csrn,
                                                     const float* __restrict__ dinv,
                                                     const float* __restrict__ bias,
                                                     unsigned short* __restrict__ outp, int n) {
    int wid = threadIdx.x >> 6, lane = threadIdx.x & 63;
    int i = blockIdx.x * 4 + wid;
    if (i >= n) return;
    int f = lane * 4;
    float di = dinv[i], w0 = di * di;
    ushort4v hv = *reinterpret_cast<const ushort4v*>(&h[(size_t)i * 256 + f]);
    float acc[4];
    #pragma unroll
    for (int j = 0; j < 4; j++) acc[j] = bf2f(hv[j]) * w0;
    int p0 = offs[i], p1 = offs[i + 1];
    if (p0 < p1) {
        int s = csrs[p0]; float w = csrn[p0];
        ushort4v v = *reinterpret_cast<const ushort4v*>(&h[(size_t)s * 256 + f]);
        for (int p = p0 + 1; p < p1; p++) {
            int s2 = csrs[p]; float w2 = csrn[p];
            ushort4v v2 = *reinterpret_cast<const ushort4v*>(&h[(size_t)s2 * 256 + f]);
            #pragma unroll
            for (int j = 0; j < 4; j++) acc[j] = fmaf(w, bf2f(v[j]), acc[j]);
            w = w2; v = v2;
        }
        #pragma unroll
        for (int j = 0; j < 4; j++) acc[j] = fmaf(w, bf2f(v[j]), acc[j]);
    }
    float4 bv = *reinterpret_cast<const float4*>(&bias[f]);
    ushort4v r;
    r[0] = f2bf(fmaxf(acc[0] + bv.x, 0.f)); r[1] = f2bf(fmaxf(acc[1] + bv.y, 0.f));
    r[2] = f2bf(fmaxf(acc[2] + bv.z, 0.f)); r[3] = f2bf(fmaxf(acc[3] + bv.w, 0.f));
    *reinterpret_cast<ushort4v*>(&outp[(size_t)i * 256 + f]) = r;
}

// ---------------- pool (sorted batch, contiguous ranges) + classifier head ----------------
__global__ __launch_bounds__(256) void pool_head_kernel(const unsigned short* __restrict__ agg2b,
                                                        const int* __restrict__ start,
                                                        const float* __restrict__ Wl,
                                                        const float* __restrict__ bl,
                                                        float* __restrict__ out) {
    __shared__ float pooled[OUT_DIM];
    int g = blockIdx.x;
    int t = threadIdx.x;
    int s0 = start[g], s1 = start[g + 1];
    float sum = 0.f;
    for (int r = s0; r < s1; r++) sum += bf2f(agg2b[(size_t)r * OUT_DIM + t]);
    pooled[t] = sum / fmaxf((float)(s1 - s0), 1.0f);
    __syncthreads();
    int c = t >> 5, j = t & 31;
    float part = 0.f;
    #pragma unroll
    for (int m = 0; m < 8; m++) {
        int k = j + m * 32;
        part = fmaf(pooled[k], Wl[k * N_CLASSES + c], part);
    }
    #pragma unroll
    for (int m = 16; m >= 1; m >>= 1) part += __shfl_xor(part, m, 32);
    if (j == 0) out[g * N_CLASSES + c] = part + bl[c];
}

extern "C" void kernel_launch(void* const* d_in, const int* in_sizes, int n_in,
                              void* d_out, int out_size, void* d_ws, size_t ws_size,
                              hipStream_t stream) {
    const float* x   = (const float*)d_in[0];
    const float* W1  = (const float*)d_in[1];
    const float* b1  = (const float*)d_in[2];
    const float* W2  = (const float*)d_in[3];
    const float* b2  = (const float*)d_in[4];
    const float* Wl  = (const float*)d_in[5];
    const float* bl  = (const float*)d_in[6];
    const int*   ei  = (const int*)d_in[7];
    const int*   bat = (const int*)d_in[8];
    float* out = (float*)d_out;

    const int n = N_NODES;
    const int E = in_sizes[7] / 2;
    const int* src = ei;
    const int* dst = ei + E;

    // workspace layout (~33 MB), 16B-aligned chunks
    unsigned short* h2b   = (unsigned short*)d_ws;                     // n*256 bf16
    unsigned short* agg2b = h2b + (size_t)n * OUT_DIM;                 // n*256 bf16
    unsigned short* h1b   = agg2b + (size_t)n * OUT_DIM;               // n*512 bf16
    unsigned short* agg1b = h1b + (size_t)n * HID_DIM;                 // n*512 bf16
    unsigned short* W1t   = agg1b + (size_t)n * HID_DIM;               // 512*512 bf16
    unsigned short* W2t   = W1t + IN_DIM * HID_DIM;                    // 256*512 bf16
    int*   cnt   = (int*)(W2t + HID_DIM * OUT_DIM);
    int*   offs  = cnt + n;                                            // n+1
    int*   pos   = offs + n + 1;                                       // n
    int*   csrs  = pos + n;                                            // E
    float* csrn  = (float*)(csrs + E);                                 // E
    float* dinv  = csrn + E;                                           // n
    int*   start = (int*)(dinv + n);                                   // N_GRAPHS+1

    hipMemsetAsync(cnt, 0, n * sizeof(int), stream);

    count_deg_kernel<<<(E + 255) / 256, 256, 0, stream>>>(dst, cnt, E);
    node_prep_kernel<<<(n + 255) / 256, 256, 0, stream>>>(cnt, dinv, n);
    scan_kernel<<<1, 1024, 0, stream>>>(cnt, offs, pos, n);
    fill_csr_kernel<<<(E + 255) / 256, 256, 0, stream>>>(src, dst, dinv, pos, csrs, csrn, E);
    bounds_kernel<<<(n + 255) / 256, 256, 0, stream>>>(bat, start, n);

    transposeW_kernel<<<dim3(HID_DIM / 32, IN_DIM / 32), dim3(32, 8), 0, stream>>>(W1, W1t, IN_DIM, HID_DIM);
    transposeW_kernel<<<dim3(OUT_DIM / 32, HID_DIM / 32), dim3(32, 8), 0, stream>>>(W2, W2t, HID_DIM, OUT_DIM);

    // layer 1: h1b = bf16(x @ W1) ; agg1b = bf16(relu(A_norm @ h1 + b1))
    dim3 g1((n + 127) / 128, HID_DIM / 64);
    mfma_gemm_kernel<128, 64, true, true><<<g1, 256, 0, stream>>>(x, W1t, h1b, n, HID_DIM, IN_DIM);
    agg512_kernel<<<(n + 3) / 4, 256, 0, stream>>>(h1b, offs, csrs, csrn, dinv, b1, agg1b, n);

    // layer 2: h2b = bf16(agg1b @ W2) ; agg2b = bf16(relu(A_norm @ h2 + b2))
    dim3 g2((n + 63) / 64, OUT_DIM / 64);
    mfma_gemm_kernel<64, 64, false, true><<<g2, 256, 0, stream>>>(agg1b, W2t, h2b, n, OUT_DIM, HID_DIM);
    agg256_kernel<<<(n + 3) / 4, 256, 0, stream>>>(h2b, offs, csrs, csrn, dinv, b2, agg2b, n);

    // pool over contiguous per-graph node ranges + head
    pool_head_kernel<<<N_GRAPHS, OUT_DIM, 0, stream>>>(agg2b, start, Wl, bl, out);
}

// Round 6
// 213.669 us; speedup vs baseline: 1.5288x; 1.1931x over previous
//
#include <hip/hip_runtime.h>

#define N_NODES   10000
#define IN_DIM    512
#define HID_DIM   512
#define OUT_DIM   256
#define N_CLASSES 8
#define N_GRAPHS  64

typedef __attribute__((ext_vector_type(8))) __bf16 bf16x8;
typedef __attribute__((ext_vector_type(4))) float f32x4;
typedef __attribute__((ext_vector_type(8))) unsigned short ushort8;
typedef __attribute__((ext_vector_type(4))) unsigned short ushort4v;

__device__ __forceinline__ unsigned short f2bf(float f) {
    union { float f; unsigned int u; } v; v.f = f;
    unsigned int r = v.u + 0x7FFFu + ((v.u >> 16) & 1u);   // RTNE
    return (unsigned short)(r >> 16);
}
__device__ __forceinline__ float bf2f(unsigned short u) {
    union { unsigned int u; float f; } v; v.u = ((unsigned int)u) << 16;
    return v.f;
}

// ---------------- degree count ----------------
__global__ void count_deg_kernel(const int* __restrict__ dst, int* __restrict__ cnt, int E) {
    int e = blockIdx.x * blockDim.x + threadIdx.x;
    if (e < E) atomicAdd(&cnt[dst[e]], 1);
}

// ---------------- dinv + graph boundaries (sorted batch) ----------------
__global__ void node_prep_kernel(const int* __restrict__ cnt, float* __restrict__ dinv,
                                 const int* __restrict__ batch, int* __restrict__ start, int n) {
    int i = blockIdx.x * blockDim.x + threadIdx.x;
    if (i < n) {
        dinv[i] = rsqrtf((float)(cnt[i] + 1));   // self-loop => deg >= 1
        int b = batch[i];
        int bn = (i + 1 < n) ? batch[i + 1] : N_GRAPHS;
        for (int g = b + 1; g <= bn; g++) start[g] = i + 1;
        if (i == 0) for (int g = 0; g <= b; g++) start[g] = 0;
    }
}

// ---------------- exclusive scan (one block) ----------------
__global__ __launch_bounds__(1024) void scan_kernel(const int* __restrict__ cnt,
                                                    int* __restrict__ offs,
                                                    int* __restrict__ pos, int n) {
    __shared__ int partial[1024];
    int tid = threadIdx.x;
    const int CH = (n + 1023) >> 10;
    int base = tid * CH;
    int s = 0;
    for (int i = 0; i < CH; i++) { int idx = base + i; if (idx < n) s += cnt[idx]; }
    partial[tid] = s;
    __syncthreads();
    for (int off = 1; off < 1024; off <<= 1) {
        int v = (tid >= off) ? partial[tid - off] : 0;
        __syncthreads();
        partial[tid] += v;
        __syncthreads();
    }
    int run = (tid > 0) ? partial[tid - 1] : 0;
    for (int i = 0; i < CH; i++) {
        int idx = base + i;
        if (idx < n) { offs[idx] = run; pos[idx] = run; run += cnt[idx]; }
    }
    if (tid == 0) offs[n] = partial[1023];
}

// ---------------- bucket edges into CSR (by dst) ----------------
__global__ void fill_csr_kernel(const int* __restrict__ src, const int* __restrict__ dst,
                                const float* __restrict__ dinv, int* __restrict__ pos,
                                int* __restrict__ csrs, float* __restrict__ csrn, int E) {
    int e = blockIdx.x * blockDim.x + threadIdx.x;
    if (e < E) {
        int s = src[e], d = dst[e];
        int p = atomicAdd(&pos[d], 1);
        csrs[p] = s;
        csrn[p] = dinv[s] * dinv[d];
    }
}

// ---------------- both weight transposes in one launch ----------------
__global__ __launch_bounds__(256) void transposeW2_kernel(const float* __restrict__ W1,
                                                          unsigned short* __restrict__ W1t,
                                                          const float* __restrict__ W2,
                                                          unsigned short* __restrict__ W2t) {
    __shared__ float t[32][33];
    int b = blockIdx.x;
    const float* W; unsigned short* Wt; int K, N, bn, bk;
    if (b < 256) { W = W1; Wt = W1t; K = IN_DIM;  N = HID_DIM; bn = (b & 15) * 32; bk = (b >> 4) * 32; }
    else { b -= 256; W = W2; Wt = W2t; K = HID_DIM; N = OUT_DIM; bn = (b & 7) * 32;  bk = (b >> 3) * 32; }
    int tx = threadIdx.x & 31, ty = threadIdx.x >> 5;   // 32 x 8
    #pragma unroll
    for (int j = 0; j < 32; j += 8)
        t[ty + j][tx] = W[(size_t)(bk + ty + j) * N + bn + tx];
    __syncthreads();
    #pragma unroll
    for (int j = 0; j < 32; j += 8)
        Wt[(size_t)(bn + ty + j) * K + bk + tx] = f2bf(t[tx][ty + j]);
}

// ---------------- x fp32 -> bf16 streaming convert ----------------
__global__ __launch_bounds__(256) void cvt_x_kernel(const float* __restrict__ x,
                                                    unsigned short* __restrict__ xb, int total8) {
    int i = blockIdx.x * blockDim.x + threadIdx.x;
    if (i < total8) {
        float4 f0 = *reinterpret_cast<const float4*>(&x[(size_t)i * 8]);
        float4 f1 = *reinterpret_cast<const float4*>(&x[(size_t)i * 8 + 4]);
        ushort8 v;
        v[0] = f2bf(f0.x); v[1] = f2bf(f0.y); v[2] = f2bf(f0.z); v[3] = f2bf(f0.w);
        v[4] = f2bf(f1.x); v[5] = f2bf(f1.y); v[6] = f2bf(f1.z); v[7] = f2bf(f1.w);
        *reinterpret_cast<ushort8*>(&xb[(size_t)i * 8]) = v;
    }
}

// ---------------- bf16 MFMA GEMM: C[M,N] = A[M,K] @ Bt[N,K]^T ----------------
// BMxBN tile, BK=32, 4 waves (2x2), (BM/32)x(BN/32) fragments of 16x16x32 per wave.
template<int BM, int BN, bool OUT_BF16>
__global__ __launch_bounds__(256) void mfma_gemm_kernel(const unsigned short* __restrict__ A,
                                                        const unsigned short* __restrict__ Bt,
                                                        void* __restrict__ Cp,
                                                        int M, int N, int K) {
    constexpr int BK = 32, PK = 40;
    constexpr int FM = BM / 32, FN = BN / 32;
    __shared__ unsigned short As[BM * PK];
    __shared__ unsigned short Bs[BN * PK];
    int tid  = threadIdx.x;
    int lane = tid & 63;
    int wid  = tid >> 6;
    int wm = wid >> 1, wn = wid & 1;
    int row0 = blockIdx.x * BM, col0 = blockIdx.y * BN;

    f32x4 acc[FM][FN] = {};

    for (int k0 = 0; k0 < K; k0 += BK) {
        #pragma unroll
        for (int i = 0; i < BM * 4 / 256; i++) {   // A: BM rows x 4 ushort8-slots
            int l  = tid + i * 256;
            int r  = l >> 2;
            int cg = (l & 3) << 3;
            int gr = row0 + r;
            ushort8 av = {0, 0, 0, 0, 0, 0, 0, 0};
            if (gr < M) av = *reinterpret_cast<const ushort8*>(&A[(size_t)gr * K + k0 + cg]);
            *reinterpret_cast<ushort8*>(&As[r * PK + cg]) = av;
        }
        #pragma unroll
        for (int i = 0; i < BN * 4 / 256; i++) {   // B: BN rows x 4 slots (N,K exact)
            int l  = tid + i * 256;
            int r  = l >> 2;
            int cg = (l & 3) << 3;
            *reinterpret_cast<ushort8*>(&Bs[r * PK + cg]) =
                *reinterpret_cast<const ushort8*>(&Bt[(size_t)(col0 + r) * K + k0 + cg]);
        }
        __syncthreads();
        int kk = (lane >> 4) << 3;
        int ra = (wm * (BM / 2) + (lane & 15)) * PK + kk;
        int rb = (wn * (BN / 2) + (lane & 15)) * PK + kk;
        bf16x8 a[FM], b[FN];
        #pragma unroll
        for (int m = 0; m < FM; m++)
            a[m] = *reinterpret_cast<const bf16x8*>(&As[ra + m * 16 * PK]);
        #pragma unroll
        for (int nn = 0; nn < FN; nn++)
            b[nn] = *reinterpret_cast<const bf16x8*>(&Bs[rb + nn * 16 * PK]);
        #pragma unroll
        for (int m = 0; m < FM; m++)
            #pragma unroll
            for (int nn = 0; nn < FN; nn++)
                acc[m][nn] = __builtin_amdgcn_mfma_f32_16x16x32_bf16(a[m], b[nn], acc[m][nn], 0, 0, 0);
        __syncthreads();
    }

    // C/D layout (HW-verified): col = lane&15, row = (lane>>4)*4 + reg
    int rbase = row0 + wm * (BM / 2) + ((lane >> 4) << 2);
    int cbase = col0 + wn * (BN / 2) + (lane & 15);
    #pragma unroll
    for (int m = 0; m < FM; m++) {
        #pragma unroll
        for (int nn = 0; nn < FN; nn++) {
            #pragma unroll
            for (int j = 0; j < 4; j++) {
                int row = rbase + m * 16 + j;
                if (row < M) {
                    int col = cbase + nn * 16;
                    if (OUT_BF16) ((unsigned short*)Cp)[(size_t)row * N + col] = f2bf(acc[m][nn][j]);
                    else          ((float*)Cp)[(size_t)row * N + col] = acc[m][nn][j];
                }
            }
        }
    }
}

// ---------------- layer-1 aggregation: wave per node, F=512, bf16 in/out ----------------
__global__ __launch_bounds__(256) void agg512_kernel(const unsigned short* __restrict__ h,
                                                     const int* __restrict__ offs,
                                                     const int* __restrict__ csrs,
                                                     const float* __restrict__ csrn,
                                                     const float* __restrict__ dinv,
                                                     const float* __restrict__ bias,
                                                     unsigned short* __restrict__ outp, int n) {
    int wid = threadIdx.x >> 6, lane = threadIdx.x & 63;
    int i = blockIdx.x * 4 + wid;
    if (i >= n) return;
    int f = lane * 8;
    float di = dinv[i], w0 = di * di;
    ushort8 hv = *reinterpret_cast<const ushort8*>(&h[(size_t)i * 512 + f]);
    float acc[8];
    #pragma unroll
    for (int j = 0; j < 8; j++) acc[j] = bf2f(hv[j]) * w0;
    int p0 = offs[i], p1 = offs[i + 1];
    if (p0 < p1) {
        int s = csrs[p0]; float w = csrn[p0];
        ushort8 v = *reinterpret_cast<const ushort8*>(&h[(size_t)s * 512 + f]);
        for (int p = p0 + 1; p < p1; p++) {
            int s2 = csrs[p]; float w2 = csrn[p];
            ushort8 v2 = *reinterpret_cast<const ushort8*>(&h[(size_t)s2 * 512 + f]);
            #pragma unroll
            for (int j = 0; j < 8; j++) acc[j] = fmaf(w, bf2f(v[j]), acc[j]);
            w = w2; v = v2;
        }
        #pragma unroll
        for (int j = 0; j < 8; j++) acc[j] = fmaf(w, bf2f(v[j]), acc[j]);
    }
    float4 b0 = *reinterpret_cast<const float4*>(&bias[f]);
    float4 b1 = *reinterpret_cast<const float4*>(&bias[f + 4]);
    ushort8 r;
    r[0] = f2bf(fmaxf(acc[0] + b0.x, 0.f)); r[1] = f2bf(fmaxf(acc[1] + b0.y, 0.f));
    r[2] = f2bf(fmaxf(acc[2] + b0.z, 0.f)); r[3] = f2bf(fmaxf(acc[3] + b0.w, 0.f));
    r[4] = f2bf(fmaxf(acc[4] + b1.x, 0.f)); r[5] = f2bf(fmaxf(acc[5] + b1.y, 0.f));
    r[6] = f2bf(fmaxf(acc[6] + b1.z, 0.f)); r[7] = f2bf(fmaxf(acc[7] + b1.w, 0.f));
    *reinterpret_cast<ushort8*>(&outp[(size_t)i * 512 + f]) = r;
}

// ---------------- layer-2 aggregation: wave per node, F=256, bf16 in/out ----------------
__global__ __launch_bounds__(256) void agg256_kernel(const unsigned short* __restrict__ h,
                                                     const int* __restrict__ offs,
                                                     const int* __restrict__ csrs,
                                                     const float* __restrict__ csrn,
                                                     const float* __restrict__ dinv,
                                                     const float* __restrict__ bias,
                                                     unsigned short* __restrict__ outp, int n) {
    int wid = threadIdx.x >> 6, lane = threadIdx.x & 63;
    int i = blockIdx.x * 4 + wid;
    if (i >= n) return;
    int f = lane * 4;
    float di = dinv[i], w0 = di * di;
    ushort4v hv = *reinterpret_cast<const ushort4v*>(&h[(size_t)i * 256 + f]);
    float acc[4];
    #pragma unroll
    for (int j = 0; j < 4; j++) acc[j] = bf2f(hv[j]) * w0;
    int p0 = offs[i], p1 = offs[i + 1];
    if (p0 < p1) {
        int s = csrs[p0]; float w = csrn[p0];
        ushort4v v = *reinterpret_cast<const ushort4v*>(&h[(size_t)s * 256 + f]);
        for (int p = p0 + 1; p < p1; p++) {
            int s2 = csrs[p]; float w2 = csrn[p];
            ushort4v v2 = *reinterpret_cast<const ushort4v*>(&h[(size_t)s2 * 256 + f]);
            #pragma unroll
            for (int j = 0; j < 4; j++) acc[j] = fmaf(w, bf2f(v[j]), acc[j]);
            w = w2; v = v2;
        }
        #pragma unroll
        for (int j = 0; j < 4; j++) acc[j] = fmaf(w, bf2f(v[j]), acc[j]);
    }
    float4 bv = *reinterpret_cast<const float4*>(&bias[f]);
    ushort4v r;
    r[0] = f2bf(fmaxf(acc[0] + bv.x, 0.f)); r[1] = f2bf(fmaxf(acc[1] + bv.y, 0.f));
    r[2] = f2bf(fmaxf(acc[2] + bv.z, 0.f)); r[3] = f2bf(fmaxf(acc[3] + bv.w, 0.f));
    *reinterpret_cast<ushort4v*>(&outp[(size_t)i * 256 + f]) = r;
}

// ---------------- pool (sorted batch, contiguous ranges) + classifier head ----------------
// thread = (row-phase ry 0..7, col-group cg of 8): ushort8 loads, 8 rows per step
__global__ __launch_bounds__(256) void pool_head_kernel(const unsigned short* __restrict__ agg2b,
                                                        const int* __restrict__ start,
                                                        const float* __restrict__ Wl,
                                                        const float* __restrict__ bl,
                                                        float* __restrict__ out) {
    __shared__ float smem[8][OUT_DIM];   // 8 KB
    int g = blockIdx.x;
    int t = threadIdx.x;
    int ry = t >> 5;            // 0..7
    int cg = (t & 31) << 3;     // 0,8,...,248
    int s0 = start[g], s1 = start[g + 1];
    float acc[8] = {};
    for (int r = s0 + ry; r < s1; r += 8) {
        ushort8 v = *reinterpret_cast<const ushort8*>(&agg2b[(size_t)r * OUT_DIM + cg]);
        #pragma unroll
        for (int j = 0; j < 8; j++) acc[j] += bf2f(v[j]);
    }
    #pragma unroll
    for (int j = 0; j < 8; j++) smem[ry][cg + j] = acc[j];
    __syncthreads();
    float inv = 1.0f / fmaxf((float)(s1 - s0), 1.0f);
    float s = 0.f;
    #pragma unroll
    for (int r2 = 0; r2 < 8; r2++) s += smem[r2][t];
    float pooled_t = s * inv;
    __syncthreads();
    smem[0][t] = pooled_t;
    __syncthreads();
    int c = t >> 5, j = t & 31;
    float part = 0.f;
    #pragma unroll
    for (int m = 0; m < 8; m++) {
        int k = j + m * 32;
        part = fmaf(smem[0][k], Wl[k * N_CLASSES + c], part);
    }
    #pragma unroll
    for (int m = 16; m >= 1; m >>= 1) part += __shfl_xor(part, m, 32);
    if (j == 0) out[g * N_CLASSES + c] = part + bl[c];
}

extern "C" void kernel_launch(void* const* d_in, const int* in_sizes, int n_in,
                              void* d_out, int out_size, void* d_ws, size_t ws_size,
                              hipStream_t stream) {
    const float* x   = (const float*)d_in[0];
    const float* W1  = (const float*)d_in[1];
    const float* b1  = (const float*)d_in[2];
    const float* W2  = (const float*)d_in[3];
    const float* b2  = (const float*)d_in[4];
    const float* Wl  = (const float*)d_in[5];
    const float* bl  = (const float*)d_in[6];
    const int*   ei  = (const int*)d_in[7];
    const int*   bat = (const int*)d_in[8];
    float* out = (float*)d_out;

    const int n = N_NODES;
    const int E = in_sizes[7] / 2;
    const int* src = ei;
    const int* dst = ei + E;

    // workspace layout, 16B-aligned chunks
    unsigned short* xb    = (unsigned short*)d_ws;                     // n*512 bf16
    unsigned short* h2b   = xb + (size_t)n * IN_DIM;                   // n*256 bf16
    unsigned short* agg2b = h2b + (size_t)n * OUT_DIM;                 // n*256 bf16
    unsigned short* h1b   = agg2b + (size_t)n * OUT_DIM;               // n*512 bf16
    unsigned short* agg1b = h1b + (size_t)n * HID_DIM;                 // n*512 bf16
    unsigned short* W1t   = agg1b + (size_t)n * HID_DIM;               // 512*512 bf16
    unsigned short* W2t   = W1t + IN_DIM * HID_DIM;                    // 256*512 bf16
    int*   cnt   = (int*)(W2t + HID_DIM * OUT_DIM);
    int*   offs  = cnt + n;                                            // n+1
    int*   pos   = offs + n + 1;                                       // n
    int*   csrs  = pos + n;                                            // E
    float* csrn  = (float*)(csrs + E);                                 // E
    float* dinv  = csrn + E;                                           // n
    int*   start = (int*)(dinv + n);                                   // N_GRAPHS+1

    hipMemsetAsync(cnt, 0, n * sizeof(int), stream);

    count_deg_kernel<<<(E + 255) / 256, 256, 0, stream>>>(dst, cnt, E);
    node_prep_kernel<<<(n + 255) / 256, 256, 0, stream>>>(cnt, dinv, bat, start, n);
    scan_kernel<<<1, 1024, 0, stream>>>(cnt, offs, pos, n);
    fill_csr_kernel<<<(E + 255) / 256, 256, 0, stream>>>(src, dst, dinv, pos, csrs, csrn, E);

    transposeW2_kernel<<<384, 256, 0, stream>>>(W1, W1t, W2, W2t);
    cvt_x_kernel<<<(n * IN_DIM / 8 + 255) / 256, 256, 0, stream>>>(x, xb, n * IN_DIM / 8);

    // layer 1: h1b = bf16(xb @ W1) ; agg1b = bf16(relu(A_norm @ h1 + b1))
    dim3 g1((n + 127) / 128, HID_DIM / 64);
    mfma_gemm_kernel<128, 64, true><<<g1, 256, 0, stream>>>(xb, W1t, h1b, n, HID_DIM, IN_DIM);
    agg512_kernel<<<(n + 3) / 4, 256, 0, stream>>>(h1b, offs, csrs, csrn, dinv, b1, agg1b, n);

    // layer 2: h2b = bf16(agg1b @ W2) ; agg2b = bf16(relu(A_norm @ h2 + b2))
    dim3 g2((n + 127) / 128, OUT_DIM / 64);
    mfma_gemm_kernel<128, 64, true><<<g2, 256, 0, stream>>>(agg1b, W2t, h2b, n, OUT_DIM, HID_DIM);
    agg256_kernel<<<(n + 3) / 4, 256, 0, stream>>>(h2b, offs, csrs, csrn, dinv, b2, agg2b, n);

    // pool over contiguous per-graph node ranges + head
    pool_head_kernel<<<N_GRAPHS, OUT_DIM, 0, stream>>>(agg2b, start, Wl, bl, out);
}

// Round 7
// 212.104 us; speedup vs baseline: 1.5401x; 1.0074x over previous
//
#include <hip/hip_runtime.h>

#define N_NODES   10000
#define IN_DIM    512
#define HID_DIM   512
#define OUT_DIM   256
#define N_CLASSES 8
#define N_GRAPHS  64

typedef __attribute__((ext_vector_type(8))) __bf16 bf16x8;
typedef __attribute__((ext_vector_type(4))) float f32x4;
typedef __attribute__((ext_vector_type(8))) unsigned short ushort8;
typedef __attribute__((ext_vector_type(4))) unsigned short ushort4v;

__device__ __forceinline__ unsigned short f2bf(float f) {
    union { float f; unsigned int u; } v; v.f = f;
    unsigned int r = v.u + 0x7FFFu + ((v.u >> 16) & 1u);   // RTNE
    return (unsigned short)(r >> 16);
}
__device__ __forceinline__ float bf2f(unsigned short u) {
    union { unsigned int u; float f; } v; v.u = ((unsigned int)u) << 16;
    return v.f;
}

// ---------------- degree count ----------------
__global__ void count_deg_kernel(const int* __restrict__ dst, int* __restrict__ cnt, int E) {
    int e = blockIdx.x * blockDim.x + threadIdx.x;
    if (e < E) atomicAdd(&cnt[dst[e]], 1);
}

// ---------------- exclusive scan + dinv + graph bounds (one block) ----------------
__global__ __launch_bounds__(1024) void scan_prep_kernel(const int* __restrict__ cnt,
                                                         int* __restrict__ offs,
                                                         int* __restrict__ pos,
                                                         float* __restrict__ dinv,
                                                         const int* __restrict__ batch,
                                                         int* __restrict__ start, int n) {
    __shared__ int partial[1024];
    int tid = threadIdx.x;
    const int CH = (n + 1023) >> 10;
    int base = tid * CH;
    int s = 0;
    for (int i = 0; i < CH; i++) { int idx = base + i; if (idx < n) s += cnt[idx]; }
    partial[tid] = s;
    __syncthreads();
    for (int off = 1; off < 1024; off <<= 1) {
        int v = (tid >= off) ? partial[tid - off] : 0;
        __syncthreads();
        partial[tid] += v;
        __syncthreads();
    }
    int run = (tid > 0) ? partial[tid - 1] : 0;
    for (int i = 0; i < CH; i++) {
        int idx = base + i;
        if (idx < n) {
            int c = cnt[idx];
            offs[idx] = run; pos[idx] = run; run += c;
            dinv[idx] = rsqrtf((float)(c + 1));     // self-loop => deg >= 1
            int b  = batch[idx];
            int bn = (idx + 1 < n) ? batch[idx + 1] : N_GRAPHS;
            for (int g = b + 1; g <= bn; g++) start[g] = idx + 1;
            if (idx == 0) for (int g = 0; g <= b; g++) start[g] = 0;
        }
    }
    if (tid == 0) offs[n] = partial[1023];
}

// ---------------- bucket edges into CSR (by dst) ----------------
__global__ void fill_csr_kernel(const int* __restrict__ src, const int* __restrict__ dst,
                                const float* __restrict__ dinv, int* __restrict__ pos,
                                int* __restrict__ csrs, float* __restrict__ csrn, int E) {
    int e = blockIdx.x * blockDim.x + threadIdx.x;
    if (e < E) {
        int s = src[e], d = dst[e];
        int p = atomicAdd(&pos[d], 1);
        csrs[p] = s;
        csrn[p] = dinv[s] * dinv[d];
    }
}

// ---------------- weight transposes + x convert, one launch ----------------
// blocks 0..255: W1 32x32 transpose tiles; 256..383: W2; 384+: x fp32->bf16
__global__ __launch_bounds__(256) void cvt_all_kernel(const float* __restrict__ W1,
                                                      unsigned short* __restrict__ W1t,
                                                      const float* __restrict__ W2,
                                                      unsigned short* __restrict__ W2t,
                                                      const float* __restrict__ x,
                                                      unsigned short* __restrict__ xb, int total8) {
    int b = blockIdx.x;
    if (b < 384) {
        __shared__ float t[32][33];
        const float* W; unsigned short* Wt; int K, N, bn, bk;
        if (b < 256) { W = W1; Wt = W1t; K = IN_DIM;  N = HID_DIM; bn = (b & 15) * 32; bk = (b >> 4) * 32; }
        else { int b2 = b - 256; W = W2; Wt = W2t; K = HID_DIM; N = OUT_DIM; bn = (b2 & 7) * 32; bk = (b2 >> 3) * 32; }
        int tx = threadIdx.x & 31, ty = threadIdx.x >> 5;   // 32 x 8
        #pragma unroll
        for (int j = 0; j < 32; j += 8)
            t[ty + j][tx] = W[(size_t)(bk + ty + j) * N + bn + tx];
        __syncthreads();
        #pragma unroll
        for (int j = 0; j < 32; j += 8)
            Wt[(size_t)(bn + ty + j) * K + bk + tx] = f2bf(t[tx][ty + j]);
    } else {
        int i = (b - 384) * 256 + threadIdx.x;
        if (i < total8) {
            float4 f0 = *reinterpret_cast<const float4*>(&x[(size_t)i * 8]);
            float4 f1 = *reinterpret_cast<const float4*>(&x[(size_t)i * 8 + 4]);
            ushort8 v;
            v[0] = f2bf(f0.x); v[1] = f2bf(f0.y); v[2] = f2bf(f0.z); v[3] = f2bf(f0.w);
            v[4] = f2bf(f1.x); v[5] = f2bf(f1.y); v[6] = f2bf(f1.z); v[7] = f2bf(f1.w);
            *reinterpret_cast<ushort8*>(&xb[(size_t)i * 8]) = v;
        }
    }
}

// ---------------- bf16 MFMA GEMM: C[M,N] = A[M,K] @ Bt[N,K]^T ----------------
template<int BM, int BN, bool OUT_BF16>
__global__ __launch_bounds__(256) void mfma_gemm_kernel(const unsigned short* __restrict__ A,
                                                        const unsigned short* __restrict__ Bt,
                                                        void* __restrict__ Cp,
                                                        int M, int N, int K) {
    constexpr int BK = 32, PK = 40;
    constexpr int FM = BM / 32, FN = BN / 32;
    __shared__ unsigned short As[BM * PK];
    __shared__ unsigned short Bs[BN * PK];
    int tid  = threadIdx.x;
    int lane = tid & 63;
    int wid  = tid >> 6;
    int wm = wid >> 1, wn = wid & 1;
    int row0 = blockIdx.x * BM, col0 = blockIdx.y * BN;

    f32x4 acc[FM][FN] = {};

    for (int k0 = 0; k0 < K; k0 += BK) {
        #pragma unroll
        for (int i = 0; i < BM * 4 / 256; i++) {
            int l  = tid + i * 256;
            int r  = l >> 2;
            int cg = (l & 3) << 3;
            int gr = row0 + r;
            ushort8 av = {0, 0, 0, 0, 0, 0, 0, 0};
            if (gr < M) av = *reinterpret_cast<const ushort8*>(&A[(size_t)gr * K + k0 + cg]);
            *reinterpret_cast<ushort8*>(&As[r * PK + cg]) = av;
        }
        #pragma unroll
        for (int i = 0; i < BN * 4 / 256; i++) {
            int l  = tid + i * 256;
            int r  = l >> 2;
            int cg = (l & 3) << 3;
            *reinterpret_cast<ushort8*>(&Bs[r * PK + cg]) =
                *reinterpret_cast<const ushort8*>(&Bt[(size_t)(col0 + r) * K + k0 + cg]);
        }
        __syncthreads();
        int kk = (lane >> 4) << 3;
        int ra = (wm * (BM / 2) + (lane & 15)) * PK + kk;
        int rb = (wn * (BN / 2) + (lane & 15)) * PK + kk;
        bf16x8 a[FM], b[FN];
        #pragma unroll
        for (int m = 0; m < FM; m++)
            a[m] = *reinterpret_cast<const bf16x8*>(&As[ra + m * 16 * PK]);
        #pragma unroll
        for (int nn = 0; nn < FN; nn++)
            b[nn] = *reinterpret_cast<const bf16x8*>(&Bs[rb + nn * 16 * PK]);
        #pragma unroll
        for (int m = 0; m < FM; m++)
            #pragma unroll
            for (int nn = 0; nn < FN; nn++)
                acc[m][nn] = __builtin_amdgcn_mfma_f32_16x16x32_bf16(a[m], b[nn], acc[m][nn], 0, 0, 0);
        __syncthreads();
    }

    // C/D layout (HW-verified): col = lane&15, row = (lane>>4)*4 + reg
    int rbase = row0 + wm * (BM / 2) + ((lane >> 4) << 2);
    int cbase = col0 + wn * (BN / 2) + (lane & 15);
    #pragma unroll
    for (int m = 0; m < FM; m++) {
        #pragma unroll
        for (int nn = 0; nn < FN; nn++) {
            #pragma unroll
            for (int j = 0; j < 4; j++) {
                int row = rbase + m * 16 + j;
                if (row < M) {
                    int col = cbase + nn * 16;
                    if (OUT_BF16) ((unsigned short*)Cp)[(size_t)row * N + col] = f2bf(acc[m][nn][j]);
                    else          ((float*)Cp)[(size_t)row * N + col] = acc[m][nn][j];
                }
            }
        }
    }
}

// ---------------- layer-1 aggregation: wave/node, F=512, 4-deep gather pipeline ----------------
__global__ __launch_bounds__(256) void agg512_kernel(const unsigned short* __restrict__ h,
                                                     const int* __restrict__ offs,
                                                     const int* __restrict__ csrs,
                                                     const float* __restrict__ csrn,
                                                     const float* __restrict__ dinv,
                                                     const float* __restrict__ bias,
                                                     unsigned short* __restrict__ outp, int n) {
    int wid = threadIdx.x >> 6, lane = threadIdx.x & 63;
    int i = blockIdx.x * 4 + wid;
    if (i >= n) return;
    int f = lane * 8;
    float di = dinv[i], w0 = di * di;
    ushort8 hv = *reinterpret_cast<const ushort8*>(&h[(size_t)i * 512 + f]);
    float acc[8];
    #pragma unroll
    for (int j = 0; j < 8; j++) acc[j] = bf2f(hv[j]) * w0;
    int p = offs[i], p1 = offs[i + 1];
    for (; p + 4 <= p1; p += 4) {
        int s0 = csrs[p], s1 = csrs[p + 1], s2 = csrs[p + 2], s3 = csrs[p + 3];
        float wa = csrn[p], wb = csrn[p + 1], wc = csrn[p + 2], wd = csrn[p + 3];
        ushort8 v0 = *reinterpret_cast<const ushort8*>(&h[(size_t)s0 * 512 + f]);
        ushort8 v1 = *reinterpret_cast<const ushort8*>(&h[(size_t)s1 * 512 + f]);
        ushort8 v2 = *reinterpret_cast<const ushort8*>(&h[(size_t)s2 * 512 + f]);
        ushort8 v3 = *reinterpret_cast<const ushort8*>(&h[(size_t)s3 * 512 + f]);
        #pragma unroll
        for (int j = 0; j < 8; j++) {
            acc[j] = fmaf(wa, bf2f(v0[j]), acc[j]);
            acc[j] = fmaf(wb, bf2f(v1[j]), acc[j]);
            acc[j] = fmaf(wc, bf2f(v2[j]), acc[j]);
            acc[j] = fmaf(wd, bf2f(v3[j]), acc[j]);
        }
    }
    for (; p < p1; p++) {
        int s = csrs[p]; float w = csrn[p];
        ushort8 v = *reinterpret_cast<const ushort8*>(&h[(size_t)s * 512 + f]);
        #pragma unroll
        for (int j = 0; j < 8; j++) acc[j] = fmaf(w, bf2f(v[j]), acc[j]);
    }
    float4 b0 = *reinterpret_cast<const float4*>(&bias[f]);
    float4 b1 = *reinterpret_cast<const float4*>(&bias[f + 4]);
    ushort8 r;
    r[0] = f2bf(fmaxf(acc[0] + b0.x, 0.f)); r[1] = f2bf(fmaxf(acc[1] + b0.y, 0.f));
    r[2] = f2bf(fmaxf(acc[2] + b0.z, 0.f)); r[3] = f2bf(fmaxf(acc[3] + b0.w, 0.f));
    r[4] = f2bf(fmaxf(acc[4] + b1.x, 0.f)); r[5] = f2bf(fmaxf(acc[5] + b1.y, 0.f));
    r[6] = f2bf(fmaxf(acc[6] + b1.z, 0.f)); r[7] = f2bf(fmaxf(acc[7] + b1.w, 0.f));
    *reinterpret_cast<ushort8*>(&outp[(size_t)i * 512 + f]) = r;
}

// ---------------- layer-2 aggregation: wave/node, F=256, 4-deep gather pipeline ----------------
__global__ __launch_bounds__(256) void agg256_kernel(const unsigned short* __restrict__ h,
                                                     const int* __restrict__ offs,
                                                     const int* __restrict__ csrs,
                                                     const float* __restrict__ csrn,
                                                     const float* __restrict__ dinv,
                                                     const float* __restrict__ bias,
                                                     unsigned short* __restrict__ outp, int n) {
    int wid = threadIdx.x >> 6, lane = threadIdx.x & 63;
    int i = blockIdx.x * 4 + wid;
    if (i >= n) return;
    int f = lane * 4;
    float di = dinv[i], w0 = di * di;
    ushort4v hv = *reinterpret_cast<const ushort4v*>(&h[(size_t)i * 256 + f]);
    float acc[4];
    #pragma unroll
    for (int j = 0; j < 4; j++) acc[j] = bf2f(hv[j]) * w0;
    int p = offs[i], p1 = offs[i + 1];
    for (; p + 4 <= p1; p += 4) {
        int s0 = csrs[p], s1 = csrs[p + 1], s2 = csrs[p + 2], s3 = csrs[p + 3];
        float wa = csrn[p], wb = csrn[p + 1], wc = csrn[p + 2], wd = csrn[p + 3];
        ushort4v v0 = *reinterpret_cast<const ushort4v*>(&h[(size_t)s0 * 256 + f]);
        ushort4v v1 = *reinterpret_cast<const ushort4v*>(&h[(size_t)s1 * 256 + f]);
        ushort4v v2 = *reinterpret_cast<const ushort4v*>(&h[(size_t)s2 * 256 + f]);
        ushort4v v3 = *reinterpret_cast<const ushort4v*>(&h[(size_t)s3 * 256 + f]);
        #pragma unroll
        for (int j = 0; j < 4; j++) {
            acc[j] = fmaf(wa, bf2f(v0[j]), acc[j]);
            acc[j] = fmaf(wb, bf2f(v1[j]), acc[j]);
            acc[j] = fmaf(wc, bf2f(v2[j]), acc[j]);
            acc[j] = fmaf(wd, bf2f(v3[j]), acc[j]);
        }
    }
    for (; p < p1; p++) {
        int s = csrs[p]; float w = csrn[p];
        ushort4v v = *reinterpret_cast<const ushort4v*>(&h[(size_t)s * 256 + f]);
        #pragma unroll
        for (int j = 0; j < 4; j++) acc[j] = fmaf(w, bf2f(v[j]), acc[j]);
    }
    float4 bv = *reinterpret_cast<const float4*>(&bias[f]);
    ushort4v r;
    r[0] = f2bf(fmaxf(acc[0] + bv.x, 0.f)); r[1] = f2bf(fmaxf(acc[1] + bv.y, 0.f));
    r[2] = f2bf(fmaxf(acc[2] + bv.z, 0.f)); r[3] = f2bf(fmaxf(acc[3] + bv.w, 0.f));
    *reinterpret_cast<ushort4v*>(&outp[(size_t)i * 256 + f]) = r;
}

// ---------------- pool (sorted batch, contiguous ranges) + classifier head ----------------
__global__ __launch_bounds__(256) void pool_head_kernel(const unsigned short* __restrict__ agg2b,
                                                        const int* __restrict__ start,
                                                        const float* __restrict__ Wl,
                                                        const float* __restrict__ bl,
                                                        float* __restrict__ out) {
    __shared__ float smem[8][OUT_DIM];   // 8 KB
    int g = blockIdx.x;
    int t = threadIdx.x;
    int ry = t >> 5;            // 0..7
    int cg = (t & 31) << 3;     // 0,8,...,248
    int s0 = start[g], s1 = start[g + 1];
    float acc[8] = {};
    for (int r = s0 + ry; r < s1; r += 8) {
        ushort8 v = *reinterpret_cast<const ushort8*>(&agg2b[(size_t)r * OUT_DIM + cg]);
        #pragma unroll
        for (int j = 0; j < 8; j++) acc[j] += bf2f(v[j]);
    }
    #pragma unroll
    for (int j = 0; j < 8; j++) smem[ry][cg + j] = acc[j];
    __syncthreads();
    float inv = 1.0f / fmaxf((float)(s1 - s0), 1.0f);
    float s = 0.f;
    #pragma unroll
    for (int r2 = 0; r2 < 8; r2++) s += smem[r2][t];
    float pooled_t = s * inv;
    __syncthreads();
    smem[0][t] = pooled_t;
    __syncthreads();
    int c = t >> 5, j = t & 31;
    float part = 0.f;
    #pragma unroll
    for (int m = 0; m < 8; m++) {
        int k = j + m * 32;
        part = fmaf(smem[0][k], Wl[k * N_CLASSES + c], part);
    }
    #pragma unroll
    for (int m = 16; m >= 1; m >>= 1) part += __shfl_xor(part, m, 32);
    if (j == 0) out[g * N_CLASSES + c] = part + bl[c];
}

extern "C" void kernel_launch(void* const* d_in, const int* in_sizes, int n_in,
                              void* d_out, int out_size, void* d_ws, size_t ws_size,
                              hipStream_t stream) {
    const float* x   = (const float*)d_in[0];
    const float* W1  = (const float*)d_in[1];
    const float* b1  = (const float*)d_in[2];
    const float* W2  = (const float*)d_in[3];
    const float* b2  = (const float*)d_in[4];
    const float* Wl  = (const float*)d_in[5];
    const float* bl  = (const float*)d_in[6];
    const int*   ei  = (const int*)d_in[7];
    const int*   bat = (const int*)d_in[8];
    float* out = (float*)d_out;

    const int n = N_NODES;
    const int E = in_sizes[7] / 2;
    const int* src = ei;
    const int* dst = ei + E;

    // workspace layout, 16B-aligned chunks
    unsigned short* xb    = (unsigned short*)d_ws;                     // n*512 bf16
    unsigned short* h2b   = xb + (size_t)n * IN_DIM;                   // n*256 bf16
    unsigned short* agg2b = h2b + (size_t)n * OUT_DIM;                 // n*256 bf16
    unsigned short* h1b   = agg2b + (size_t)n * OUT_DIM;               // n*512 bf16
    unsigned short* agg1b = h1b + (size_t)n * HID_DIM;                 // n*512 bf16
    unsigned short* W1t   = agg1b + (size_t)n * HID_DIM;               // 512*512 bf16
    unsigned short* W2t   = W1t + IN_DIM * HID_DIM;                    // 256*512 bf16
    int*   cnt   = (int*)(W2t + HID_DIM * OUT_DIM);
    int*   offs  = cnt + n;                                            // n+1
    int*   pos   = offs + n + 1;                                       // n
    int*   csrs  = pos + n;                                            // E
    float* csrn  = (float*)(csrs + E);                                 // E
    float* dinv  = csrn + E;                                           // n
    int*   start = (int*)(dinv + n);                                   // N_GRAPHS+1

    hipMemsetAsync(cnt, 0, n * sizeof(int), stream);

    count_deg_kernel<<<(E + 255) / 256, 256, 0, stream>>>(dst, cnt, E);
    scan_prep_kernel<<<1, 1024, 0, stream>>>(cnt, offs, pos, dinv, bat, start, n);
    fill_csr_kernel<<<(E + 255) / 256, 256, 0, stream>>>(src, dst, dinv, pos, csrs, csrn, E);

    int total8 = n * IN_DIM / 8;
    cvt_all_kernel<<<384 + (total8 + 255) / 256, 256, 0, stream>>>(W1, W1t, W2, W2t, x, xb, total8);

    // layer 1: h1b = bf16(xb @ W1) ; agg1b = bf16(relu(A_norm @ h1 + b1))
    dim3 g1((n + 127) / 128, HID_DIM / 64);
    mfma_gemm_kernel<128, 64, true><<<g1, 256, 0, stream>>>(xb, W1t, h1b, n, HID_DIM, IN_DIM);
    agg512_kernel<<<(n + 3) / 4, 256, 0, stream>>>(h1b, offs, csrs, csrn, dinv, b1, agg1b, n);

    // layer 2: h2b = bf16(agg1b @ W2) ; agg2b = bf16(relu(A_norm @ h2 + b2))
    dim3 g2((n + 127) / 128, OUT_DIM / 64);
    mfma_gemm_kernel<128, 64, true><<<g2, 256, 0, stream>>>(agg1b, W2t, h2b, n, OUT_DIM, HID_DIM);
    agg256_kernel<<<(n + 3) / 4, 256, 0, stream>>>(h2b, offs, csrs, csrn, dinv, b2, agg2b, n);

    // pool over contiguous per-graph node ranges + head
    pool_head_kernel<<<N_GRAPHS, OUT_DIM, 0, stream>>>(agg2b, start, Wl, bl, out);
}

// Round 10
// 208.856 us; speedup vs baseline: 1.5640x; 1.0156x over previous
//
#include <hip/hip_runtime.h>

#define N_NODES   10000
#define IN_DIM    512
#define HID_DIM   512
#define OUT_DIM   256
#define N_CLASSES 8
#define N_GRAPHS  64

typedef __attribute__((ext_vector_type(8))) __bf16 bf16x8;
typedef __attribute__((ext_vector_type(4))) float f32x4;
typedef __attribute__((ext_vector_type(8))) unsigned short ushort8;
typedef __attribute__((ext_vector_type(4))) unsigned short ushort4v;

__device__ __forceinline__ unsigned short f2bf(float f) {
    union { float f; unsigned int u; } v; v.f = f;
    unsigned int r = v.u + 0x7FFFu + ((v.u >> 16) & 1u);   // RTNE
    return (unsigned short)(r >> 16);
}
__device__ __forceinline__ float bf2f(unsigned short u) {
    union { unsigned int u; float f; } v; v.u = ((unsigned int)u) << 16;
    return v.f;
}

// async global->LDS, 16B per lane; LDS dest is wave-uniform base + lane*16
__device__ __forceinline__ void gload16(const unsigned short* g, unsigned short* l) {
    __builtin_amdgcn_global_load_lds(
        (const __attribute__((address_space(1))) unsigned int*)g,
        (__attribute__((address_space(3))) unsigned int*)l, 16, 0, 0);
}

// ---------------- degree count ----------------
__global__ void count_deg_kernel(const int* __restrict__ dst, int* __restrict__ cnt, int E) {
    int e = blockIdx.x * blockDim.x + threadIdx.x;
    if (e < E) atomicAdd(&cnt[dst[e]], 1);
}

// ---------------- exclusive scan + dinv + graph bounds (one block) ----------------
__global__ __launch_bounds__(1024) void scan_prep_kernel(const int* __restrict__ cnt,
                                                         int* __restrict__ offs,
                                                         int* __restrict__ pos,
                                                         float* __restrict__ dinv,
                                                         const int* __restrict__ batch,
                                                         int* __restrict__ start, int n) {
    __shared__ int partial[1024];
    int tid = threadIdx.x;
    const int CH = (n + 1023) >> 10;
    int base = tid * CH;
    int s = 0;
    for (int i = 0; i < CH; i++) { int idx = base + i; if (idx < n) s += cnt[idx]; }
    partial[tid] = s;
    __syncthreads();
    for (int off = 1; off < 1024; off <<= 1) {
        int v = (tid >= off) ? partial[tid - off] : 0;
        __syncthreads();
        partial[tid] += v;
        __syncthreads();
    }
    int run = (tid > 0) ? partial[tid - 1] : 0;
    for (int i = 0; i < CH; i++) {
        int idx = base + i;
        if (idx < n) {
            int c = cnt[idx];
            offs[idx] = run; pos[idx] = run; run += c;
            dinv[idx] = rsqrtf((float)(c + 1));     // self-loop => deg >= 1
            int b  = batch[idx];
            int bn = (idx + 1 < n) ? batch[idx + 1] : N_GRAPHS;
            for (int g = b + 1; g <= bn; g++) start[g] = idx + 1;
            if (idx == 0) for (int g = 0; g <= b; g++) start[g] = 0;
        }
    }
    if (tid == 0) offs[n] = partial[1023];
}

// ---------------- bucket edges into CSR (by dst) ----------------
__global__ void fill_csr_kernel(const int* __restrict__ src, const int* __restrict__ dst,
                                const float* __restrict__ dinv, int* __restrict__ pos,
                                int* __restrict__ csrs, float* __restrict__ csrn, int E) {
    int e = blockIdx.x * blockDim.x + threadIdx.x;
    if (e < E) {
        int s = src[e], d = dst[e];
        int p = atomicAdd(&pos[d], 1);
        csrs[p] = s;
        csrn[p] = dinv[s] * dinv[d];
    }
}

// ---------------- weight transposes + x convert, one launch ----------------
__global__ __launch_bounds__(256) void cvt_all_kernel(const float* __restrict__ W1,
                                                      unsigned short* __restrict__ W1t,
                                                      const float* __restrict__ W2,
                                                      unsigned short* __restrict__ W2t,
                                                      const float* __restrict__ x,
                                                      unsigned short* __restrict__ xb, int total8) {
    int b = blockIdx.x;
    if (b < 384) {
        __shared__ float t[32][33];
        const float* W; unsigned short* Wt; int K, N, bn, bk;
        if (b < 256) { W = W1; Wt = W1t; K = IN_DIM;  N = HID_DIM; bn = (b & 15) * 32; bk = (b >> 4) * 32; }
        else { int b2 = b - 256; W = W2; Wt = W2t; K = HID_DIM; N = OUT_DIM; bn = (b2 & 7) * 32; bk = (b2 >> 3) * 32; }
        int tx = threadIdx.x & 31, ty = threadIdx.x >> 5;   // 32 x 8
        #pragma unroll
        for (int j = 0; j < 32; j += 8)
            t[ty + j][tx] = W[(size_t)(bk + ty + j) * N + bn + tx];
        __syncthreads();
        #pragma unroll
        for (int j = 0; j < 32; j += 8)
            Wt[(size_t)(bn + ty + j) * K + bk + tx] = f2bf(t[tx][ty + j]);
    } else {
        int i = (b - 384) * 256 + threadIdx.x;
        if (i < total8) {
            float4 f0 = *reinterpret_cast<const float4*>(&x[(size_t)i * 8]);
            float4 f1 = *reinterpret_cast<const float4*>(&x[(size_t)i * 8 + 4]);
            ushort8 v;
            v[0] = f2bf(f0.x); v[1] = f2bf(f0.y); v[2] = f2bf(f0.z); v[3] = f2bf(f0.w);
            v[4] = f2bf(f1.x); v[5] = f2bf(f1.y); v[6] = f2bf(f1.z); v[7] = f2bf(f1.w);
            *reinterpret_cast<ushort8*>(&xb[(size_t)i * 8]) = v;
        }
    }
}

// ---------------- bf16 MFMA GEMM (m97 structure): C[M,N] = A[M,K] @ Bt[N,K]^T ----------------
// Linear LDS [rows][32] bf16, global_load_lds width-16 staging, BK=32,
// 4 waves (2x2), (BM/32)x(BN/32) 16x16x32 fragments per wave.
// NOTE: A-tile rows past M read garbage (adjacent ws regions) — those C rows
// are never stored; garbage A-rows only affect garbage C-rows.
template<int BM, int BN>
__global__ __launch_bounds__(256) void mfma_gemm_kernel(const unsigned short* __restrict__ A,
                                                        const unsigned short* __restrict__ Bt,
                                                        unsigned short* __restrict__ C,
                                                        int M, int N, int K) {
    constexpr int BK = 32;
    constexpr int FM = BM / 32, FN = BN / 32;
    __shared__ unsigned short As[BM * BK];
    __shared__ unsigned short Bs[BN * BK];
    int tid  = threadIdx.x;
    int lane = tid & 63;
    int wid  = tid >> 6;
    int wm = wid >> 1, wn = wid & 1;
    int row0 = blockIdx.x * BM, col0 = blockIdx.y * BN;

    f32x4 acc[FM][FN] = {};

    for (int k0 = 0; k0 < K; k0 += BK) {
        // stage A: BM*4 16B-slots, slot s -> row s>>2, k-group (s&3)*8
        #pragma unroll
        for (int i = 0; i < BM / 64; i++) {
            int sb = (wid * (BM / 64) + i) * 64;          // wave-uniform slot base
            int s  = sb + lane;
            gload16(&A[(size_t)(row0 + (s >> 2)) * K + k0 + ((s & 3) << 3)], &As[sb * 8]);
        }
        // stage B
        #pragma unroll
        for (int i = 0; i < BN / 64; i++) {
            int sb = (wid * (BN / 64) + i) * 64;
            int s  = sb + lane;
            gload16(&Bt[(size_t)(col0 + (s >> 2)) * K + k0 + ((s & 3) << 3)], &Bs[sb * 8]);
        }
        __syncthreads();   // compiler drains vmcnt before s_barrier

        int kk = (lane >> 4) << 3;
        int ra = (wm * (BM / 2) + (lane & 15)) * BK + kk;
        int rb = (wn * (BN / 2) + (lane & 15)) * BK + kk;
        bf16x8 a[FM], b[FN];
        #pragma unroll
        for (int m = 0; m < FM; m++)
            a[m] = *reinterpret_cast<const bf16x8*>(&As[ra + m * 16 * BK]);
        #pragma unroll
        for (int nn = 0; nn < FN; nn++)
            b[nn] = *reinterpret_cast<const bf16x8*>(&Bs[rb + nn * 16 * BK]);
        #pragma unroll
        for (int m = 0; m < FM; m++)
            #pragma unroll
            for (int nn = 0; nn < FN; nn++)
                acc[m][nn] = __builtin_amdgcn_mfma_f32_16x16x32_bf16(a[m], b[nn], acc[m][nn], 0, 0, 0);
        __syncthreads();
    }

    // C/D layout (HW-verified): col = lane&15, row = (lane>>4)*4 + reg
    int rbase = row0 + wm * (BM / 2) + ((lane >> 4) << 2);
    int cbase = col0 + wn * (BN / 2) + (lane & 15);
    #pragma unroll
    for (int m = 0; m < FM; m++) {
        #pragma unroll
        for (int nn = 0; nn < FN; nn++) {
            #pragma unroll
            for (int j = 0; j < 4; j++) {
                int row = rbase + m * 16 + j;
                if (row < M) C[(size_t)row * N + cbase + nn * 16] = f2bf(acc[m][nn][j]);
            }
        }
    }
}

// ---------------- layer-1 aggregation: wave/node, F=512, 4-deep gather pipeline ----------------
__global__ __launch_bounds__(256) void agg512_kernel(const unsigned short* __restrict__ h,
                                                     const int* __restrict__ offs,
                                                     const int* __restrict__ csrs,
                                                     const float* __restrict__ csrn,
                                                     const float* __restrict__ dinv,
                                                     const float* __restrict__ bias,
                                                     unsigned short* __restrict__ outp, int n) {
    int wid = threadIdx.x >> 6, lane = threadIdx.x & 63;
    int i = blockIdx.x * 4 + wid;
    if (i >= n) return;
    int f = lane * 8;
    float di = dinv[i], w0 = di * di;
    ushort8 hv = *reinterpret_cast<const ushort8*>(&h[(size_t)i * 512 + f]);
    float acc[8];
    #pragma unroll
    for (int j = 0; j < 8; j++) acc[j] = bf2f(hv[j]) * w0;
    int p = offs[i], p1 = offs[i + 1];
    for (; p + 4 <= p1; p += 4) {
        int s0 = csrs[p], s1 = csrs[p + 1], s2 = csrs[p + 2], s3 = csrs[p + 3];
        float wa = csrn[p], wb = csrn[p + 1], wc = csrn[p + 2], wd = csrn[p + 3];
        ushort8 v0 = *reinterpret_cast<const ushort8*>(&h[(size_t)s0 * 512 + f]);
        ushort8 v1 = *reinterpret_cast<const ushort8*>(&h[(size_t)s1 * 512 + f]);
        ushort8 v2 = *reinterpret_cast<const ushort8*>(&h[(size_t)s2 * 512 + f]);
        ushort8 v3 = *reinterpret_cast<const ushort8*>(&h[(size_t)s3 * 512 + f]);
        #pragma unroll
        for (int j = 0; j < 8; j++) {
            acc[j] = fmaf(wa, bf2f(v0[j]), acc[j]);
            acc[j] = fmaf(wb, bf2f(v1[j]), acc[j]);
            acc[j] = fmaf(wc, bf2f(v2[j]), acc[j]);
            acc[j] = fmaf(wd, bf2f(v3[j]), acc[j]);
        }
    }
    for (; p < p1; p++) {
        int s = csrs[p]; float w = csrn[p];
        ushort8 v = *reinterpret_cast<const ushort8*>(&h[(size_t)s * 512 + f]);
        #pragma unroll
        for (int j = 0; j < 8; j++) acc[j] = fmaf(w, bf2f(v[j]), acc[j]);
    }
    float4 b0 = *reinterpret_cast<const float4*>(&bias[f]);
    float4 b1 = *reinterpret_cast<const float4*>(&bias[f + 4]);
    ushort8 r;
    r[0] = f2bf(fmaxf(acc[0] + b0.x, 0.f)); r[1] = f2bf(fmaxf(acc[1] + b0.y, 0.f));
    r[2] = f2bf(fmaxf(acc[2] + b0.z, 0.f)); r[3] = f2bf(fmaxf(acc[3] + b0.w, 0.f));
    r[4] = f2bf(fmaxf(acc[4] + b1.x, 0.f)); r[5] = f2bf(fmaxf(acc[5] + b1.y, 0.f));
    r[6] = f2bf(fmaxf(acc[6] + b1.z, 0.f)); r[7] = f2bf(fmaxf(acc[7] + b1.w, 0.f));
    *reinterpret_cast<ushort8*>(&outp[(size_t)i * 512 + f]) = r;
}

// ---------------- layer-2 aggregation: wave/node, F=256, 4-deep gather pipeline ----------------
__global__ __launch_bounds__(256) void agg256_kernel(const unsigned short* __restrict__ h,
                                                     const int* __restrict__ offs,
                                                     const int* __restrict__ csrs,
                                                     const float* __restrict__ csrn,
                                                     const float* __restrict__ dinv,
                                                     const float* __restrict__ bias,
                                                     unsigned short* __restrict__ outp, int n) {
    int wid = threadIdx.x >> 6, lane = threadIdx.x & 63;
    int i = blockIdx.x * 4 + wid;
    if (i >= n) return;
    int f = lane * 4;
    float di = dinv[i], w0 = di * di;
    ushort4v hv = *reinterpret_cast<const ushort4v*>(&h[(size_t)i * 256 + f]);
    float acc[4];
    #pragma unroll
    for (int j = 0; j < 4; j++) acc[j] = bf2f(hv[j]) * w0;
    int p = offs[i], p1 = offs[i + 1];
    for (; p + 4 <= p1; p += 4) {
        int s0 = csrs[p], s1 = csrs[p + 1], s2 = csrs[p + 2], s3 = csrs[p + 3];
        float wa = csrn[p], wb = csrn[p + 1], wc = csrn[p + 2], wd = csrn[p + 3];
        ushort4v v0 = *reinterpret_cast<const ushort4v*>(&h[(size_t)s0 * 256 + f]);
        ushort4v v1 = *reinterpret_cast<const ushort4v*>(&h[(size_t)s1 * 256 + f]);
        ushort4v v2 = *reinterpret_cast<const ushort4v*>(&h[(size_t)s2 * 256 + f]);
        ushort4v v3 = *reinterpret_cast<const ushort4v*>(&h[(size_t)s3 * 256 + f]);
        #pragma unroll
        for (int j = 0; j < 4; j++) {
            acc[j] = fmaf(wa, bf2f(v0[j]), acc[j]);
            acc[j] = fmaf(wb, bf2f(v1[j]), acc[j]);
            acc[j] = fmaf(wc, bf2f(v2[j]), acc[j]);
            acc[j] = fmaf(wd, bf2f(v3[j]), acc[j]);
        }
    }
    for (; p < p1; p++) {
        int s = csrs[p]; float w = csrn[p];
        ushort4v v = *reinterpret_cast<const ushort4v*>(&h[(size_t)s * 256 + f]);
        #pragma unroll
        for (int j = 0; j < 4; j++) acc[j] = fmaf(w, bf2f(v[j]), acc[j]);
    }
    float4 bv = *reinterpret_cast<const float4*>(&bias[f]);
    ushort4v r;
    r[0] = f2bf(fmaxf(acc[0] + bv.x, 0.f)); r[1] = f2bf(fmaxf(acc[1] + bv.y, 0.f));
    r[2] = f2bf(fmaxf(acc[2] + bv.z, 0.f)); r[3] = f2bf(fmaxf(acc[3] + bv.w, 0.f));
    *reinterpret_cast<ushort4v*>(&outp[(size_t)i * 256 + f]) = r;
}

// ---------------- pool (sorted batch, contiguous ranges) + classifier head ----------------
__global__ __launch_bounds__(256) void pool_head_kernel(const unsigned short* __restrict__ agg2b,
                                                        const int* __restrict__ start,
                                                        const float* __restrict__ Wl,
                                                        const float* __restrict__ bl,
                                                        float* __restrict__ out) {
    __shared__ float smem[8][OUT_DIM];   // 8 KB
    int g = blockIdx.x;
    int t = threadIdx.x;
    int ry = t >> 5;            // 0..7
    int cg = (t & 31) << 3;     // 0,8,...,248
    int s0 = start[g], s1 = start[g + 1];
    float acc[8] = {};
    for (int r = s0 + ry; r < s1; r += 8) {
        ushort8 v = *reinterpret_cast<const ushort8*>(&agg2b[(size_t)r * OUT_DIM + cg]);
        #pragma unroll
        for (int j = 0; j < 8; j++) acc[j] += bf2f(v[j]);
    }
    #pragma unroll
    for (int j = 0; j < 8; j++) smem[ry][cg + j] = acc[j];
    __syncthreads();
    float inv = 1.0f / fmaxf((float)(s1 - s0), 1.0f);
    float s = 0.f;
    #pragma unroll
    for (int r2 = 0; r2 < 8; r2++) s += smem[r2][t];
    float pooled_t = s * inv;
    __syncthreads();
    smem[0][t] = pooled_t;
    __syncthreads();
    int c = t >> 5, j = t & 31;
    float part = 0.f;
    #pragma unroll
    for (int m = 0; m < 8; m++) {
        int k = j + m * 32;
        part = fmaf(smem[0][k], Wl[k * N_CLASSES + c], part);
    }
    #pragma unroll
    for (int m = 16; m >= 1; m >>= 1) part += __shfl_xor(part, m, 32);
    if (j == 0) out[g * N_CLASSES + c] = part + bl[c];
}

extern "C" void kernel_launch(void* const* d_in, const int* in_sizes, int n_in,
                              void* d_out, int out_size, void* d_ws, size_t ws_size,
                              hipStream_t stream) {
    const float* x   = (const float*)d_in[0];
    const float* W1  = (const float*)d_in[1];
    const float* b1  = (const float*)d_in[2];
    const float* W2  = (const float*)d_in[3];
    const float* b2  = (const float*)d_in[4];
    const float* Wl  = (const float*)d_in[5];
    const float* bl  = (const float*)d_in[6];
    const int*   ei  = (const int*)d_in[7];
    const int*   bat = (const int*)d_in[8];
    float* out = (float*)d_out;

    const int n = N_NODES;
    const int E = in_sizes[7] / 2;
    const int* src = ei;
    const int* dst = ei + E;

    // workspace layout, 16B-aligned chunks
    unsigned short* xb    = (unsigned short*)d_ws;                     // n*512 bf16
    unsigned short* h2b   = xb + (size_t)n * IN_DIM;                   // n*256 bf16
    unsigned short* agg2b = h2b + (size_t)n * OUT_DIM;                 // n*256 bf16
    unsigned short* h1b   = agg2b + (size_t)n * OUT_DIM;               // n*512 bf16
    unsigned short* agg1b = h1b + (size_t)n * HID_DIM;                 // n*512 bf16
    unsigned short* W1t   = agg1b + (size_t)n * HID_DIM;               // 512*512 bf16
    unsigned short* W2t   = W1t + IN_DIM * HID_DIM;                    // 256*512 bf16
    int*   cnt   = (int*)(W2t + HID_DIM * OUT_DIM);
    int*   offs  = cnt + n;                                            // n+1
    int*   pos   = offs + n + 1;                                       // n
    int*   csrs  = pos + n;                                            // E
    float* csrn  = (float*)(csrs + E);                                 // E
    float* dinv  = csrn + E;                                           // n
    int*   start = (int*)(dinv + n);                                   // N_GRAPHS+1

    hipMemsetAsync(cnt, 0, n * sizeof(int), stream);

    count_deg_kernel<<<(E + 255) / 256, 256, 0, stream>>>(dst, cnt, E);
    scan_prep_kernel<<<1, 1024, 0, stream>>>(cnt, offs, pos, dinv, bat, start, n);
    fill_csr_kernel<<<(E + 255) / 256, 256, 0, stream>>>(src, dst, dinv, pos, csrs, csrn, E);

    int total8 = n * IN_DIM / 8;
    cvt_all_kernel<<<384 + (total8 + 255) / 256, 256, 0, stream>>>(W1, W1t, W2, W2t, x, xb, total8);

    // layer 1: h1b = bf16(xb @ W1) ; agg1b = bf16(relu(A_norm @ h1 + b1))
    dim3 g1((n + 127) / 128, HID_DIM / 128);
    mfma_gemm_kernel<128, 128><<<g1, 256, 0, stream>>>(xb, W1t, h1b, n, HID_DIM, IN_DIM);
    agg512_kernel<<<(n + 3) / 4, 256, 0, stream>>>(h1b, offs, csrs, csrn, dinv, b1, agg1b, n);

    // layer 2: h2b = bf16(agg1b @ W2) ; agg2b = bf16(relu(A_norm @ h2 + b2))
    dim3 g2((n + 127) / 128, OUT_DIM / 64);
    mfma_gemm_kernel<128, 64><<<g2, 256, 0, stream>>>(agg1b, W2t, h2b, n, OUT_DIM, HID_DIM);
    agg256_kernel<<<(n + 3) / 4, 256, 0, stream>>>(h2b, offs, csrs, csrn, dinv, b2, agg2b, n);

    // pool over contiguous per-graph node ranges + head
    pool_head_kernel<<<N_GRAPHS, OUT_DIM, 0, stream>>>(agg2b, start, Wl, bl, out);
}